// Round 8
// baseline (3103.439 us; speedup 1.0000x reference)
//
#include <hip/hip_runtime.h>
#include <hip/hip_bf16.h>

// Sizes (fixed): T=512 tokens, D=256 embed, L=256 lstm, H=512 hidden. 4L=1024.

typedef _Float16 h2v __attribute__((ext_vector_type(2)));

#define BC(x) __builtin_bit_cast(h2v, (x))

__device__ __forceinline__ float fdot2f(h2v a, h2v b, float c) {
#if __has_builtin(__builtin_amdgcn_fdot2)
    return __builtin_amdgcn_fdot2(a, b, c, false);
#else
    return c + (float)a[0] * (float)b[0] + (float)a[1] * (float)b[1];
#endif
}

// ---------------------------------------------------------------------------
// prep4: convert all four U [256 x 1024] f32 -> packed half2 (k-pair, col).
// Uf[m][k2*1024 + col] = (U[2k2][col], U[2k2+1][col]) as 2xf16 in a uint.
// ---------------------------------------------------------------------------
__global__ __launch_bounds__(256) void prep4(const float* __restrict__ U0,
                                             const float* __restrict__ U1,
                                             const float* __restrict__ U2,
                                             const float* __restrict__ U3,
                                             unsigned int* __restrict__ Uf) {
    int which = blockIdx.x >> 9;
    const float* U = which == 0 ? U0 : which == 1 ? U1 : which == 2 ? U2 : U3;
    unsigned int* out = Uf + which * 131072;
    int idx = (blockIdx.x & 511) * 256 + threadIdx.x;  // < 131072
    int k2 = idx >> 10, col = idx & 1023;
    union { _Float16 h[2]; unsigned int u; } p;
    p.h[0] = (_Float16)U[(2 * k2) * 1024 + col];
    p.h[1] = (_Float16)U[(2 * k2 + 1) * 1024 + col];
    out[idx] = p.u;
}

// ---------------------------------------------------------------------------
// gemm_cat: fused fwd/bwd GEMM with virtual concat A.
// A(row) = [A0[rr*halfK ..], A1[(M-1-rr)*halfK ..]], rr = rev? M-1-row : row.
// blockIdx.z selects (B, bias, C, rev = z && revZ1).
// ---------------------------------------------------------------------------
__global__ __launch_bounds__(256) void gemm_cat(
        const float* __restrict__ A0, const float* __restrict__ A1, int halfK,
        const float* __restrict__ Bz0, const float* __restrict__ Bz1,
        const float* __restrict__ bias0, const float* __restrict__ bias1,
        float* __restrict__ C0, float* __restrict__ C1,
        int M, int N, int K, int revZ1) {
    const float* B = blockIdx.z ? Bz1 : Bz0;
    const float* bias = blockIdx.z ? bias1 : bias0;
    float* C = blockIdx.z ? C1 : C0;
    int rev = blockIdx.z ? revZ1 : 0;

    __shared__ float sA[16][65];
    __shared__ float sB[16][65];
    int tid = threadIdx.x;
    int bm = blockIdx.y * 64, bn = blockIdx.x * 64;
    int tx = tid & 15, ty = tid >> 4;
    float acc[4][4] = {};
    for (int k0 = 0; k0 < K; k0 += 16) {
#pragma unroll
        for (int l = 0; l < 4; l++) {
            int flat = tid + 256 * l;        // 64 rows x 16 k
            int ml = flat >> 4, kk = flat & 15;
            int row = bm + ml;
            int rr = rev ? M - 1 - row : row;
            int kcol = k0 + kk;
            float val = (kcol < halfK) ? A0[rr * halfK + kcol]
                                       : A1[(M - 1 - rr) * halfK + kcol - halfK];
            sA[kk][ml] = val;
        }
#pragma unroll
        for (int l = 0; l < 4; l++) {
            int flat = tid + 256 * l;        // 16 k x 64 n
            int kk = flat >> 6, nl = flat & 63;
            sB[kk][nl] = B[(k0 + kk) * N + bn + nl];
        }
        __syncthreads();
#pragma unroll
        for (int kk = 0; kk < 16; kk++) {
            float a[4], b[4];
#pragma unroll
            for (int i = 0; i < 4; i++) a[i] = sA[kk][ty + 16 * i];
#pragma unroll
            for (int j = 0; j < 4; j++) b[j] = sB[kk][tx + 16 * j];
#pragma unroll
            for (int i = 0; i < 4; i++)
#pragma unroll
                for (int j = 0; j < 4; j++) acc[i][j] += a[i] * b[j];
        }
        __syncthreads();
    }
#pragma unroll
    for (int i = 0; i < 4; i++) {
        int r = bm + ty + 16 * i;
#pragma unroll
        for (int j = 0; j < 4; j++) {
            int cidx = bn + tx + 16 * j;
            float bv = bias ? bias[cidx] : 0.f;
            C[r * N + cidx] = acc[i][j] + bv;
        }
    }
}

// ---------------------------------------------------------------------------
// lstm_sync: 8 blocks = 2 directions x 4 groups, 512 threads each.
// Group g owns hidden units [g*64,(g+1)*64) = 256 gate columns; its U slice
// (128 kp x 256 cols x 4B = 128KB) lives ENTIRELY IN LDS. Thread t covers
// local column lc=t&255 (gate-major: lc=G*64+u), k-half hh=t>>8.
//
// Rounds 1-7 lesson (final): the backend will not keep a large loop-
// invariant array in VGPRs under any coaxing (512thr->picked 44-128 regs,
// always remat/spill through scratch-L2, ~1200us invariant). So U goes to
// LDS only; registers hold just the working set (~30). LDS reads are
// conflict-free (lane-consecutive cols, 2 lanes/bank = free; h chunk is
// wave-uniform broadcast).
//
// Per step: dot partials (P folded into acc) -> sPart -> sync -> owner wave
// (t<64) reads 8 partials, does gates + c,h update, writes h slice to
// Hb[parity] + Od -> t==0 fence + release atomicAdd cnt[s] + spin until all
// 4 groups arrive -> sync -> t<128 reload full h (L1-bypassing b64 atomic),
// pack f16 -> sHp -> sync. Parity double-buffer + per-step counters (memset
// before launch) keep it safe; 8 blocks trivially co-resident.
// ---------------------------------------------------------------------------
#define GROUPS 4

__global__ __launch_bounds__(512, 2) void lstm_sync(
        const unsigned int* __restrict__ Uf,   // [2][128*1024] packed half2
        const float* __restrict__ P,           // [2][512*1024]
        float* __restrict__ Out,               // [2][512*256]
        float* __restrict__ Hb,                // [2 parity][2 dir][256]
        int* __restrict__ cnt) {               // [2 dir][512], zeroed
    int dir = blockIdx.x >> 2;
    int g   = blockIdx.x & 3;
    const unsigned int* U = Uf + dir * 131072;
    const float* Pd = P + dir * (512 * 1024);
    float* Od = Out + dir * (512 * 256);
    int* cn = cnt + dir * 512;

    int t = threadIdx.x;
    int lc = t & 255;            // local column, gate-major (G*64+u)
    int hh = t >> 8;             // k-half, wave-uniform
    int G = lc >> 6, u = lc & 63;
    int gcol = G * 256 + g * 64 + u;   // global gate column

    __shared__ unsigned sU[128 * 256];   // 128KB: sU[kp*256 + lc]
    __shared__ unsigned sHp[128];        // h as packed f16 pairs
    __shared__ float sPart[512];

    // stage this group's U slice into LDS (one-time, coalesced 256B rows)
    for (int idx = t; idx < 128 * 256; idx += 512) {
        int kp = idx >> 8, l = idx & 255;
        sU[idx] = U[kp * 1024 + (l >> 6) * 256 + g * 64 + (l & 63)];
    }
    if (t < 128) sHp[t] = 0u;
    float cst = 0.f;
    __syncthreads();

    float pc = (t < 256) ? Pd[gcol] : 0.f;   // P folded into hh=0 partial
    for (int s = 0; s < 512; s++) {
        float pn = (s < 511 && t < 256) ? Pd[(s + 1) * 1024 + gcol] : 0.f;
        float a0 = pc, a1 = 0.f;
        const uint4* hp4 = (const uint4*)sHp;
#pragma unroll
        for (int i = 0; i < 16; i++) {
            uint4 hc = hp4[hh * 16 + i];             // wave-uniform broadcast
            int kb = (hh * 64 + 4 * i) * 256 + lc;
            a0 = fdot2f(BC(hc.x), BC(sU[kb]),       a0);
            a1 = fdot2f(BC(hc.y), BC(sU[kb + 256]), a1);
            a0 = fdot2f(BC(hc.z), BC(sU[kb + 512]), a0);
            a1 = fdot2f(BC(hc.w), BC(sU[kb + 768]), a1);
        }
        sPart[t] = a0 + a1;
        __syncthreads();
        int par = s & 1;
        float* hb = &Hb[(par * 2 + dir) * 256];
        if (t < 64) {   // owner wave: gates + cell update for 64 units
            float zi = sPart[t]       + sPart[t + 256];
            float zf = sPart[64 + t]  + sPart[320 + t];
            float zg = sPart[128 + t] + sPart[384 + t];
            float zo = sPart[192 + t] + sPart[448 + t];
            float ig = 1.f / (1.f + __expf(-zi));
            float fg = 1.f / (1.f + __expf(-zf));
            float gg = 1.f - 2.f / (1.f + __expf(2.f * zg));   // tanh
            float og = 1.f / (1.f + __expf(-zo));
            cst = fg * cst + ig * gg;
            float h = og * (1.f - 2.f / (1.f + __expf(2.f * cst)));
            hb[g * 64 + t] = h;
            Od[s * 256 + g * 64 + t] = h;
        }
        if (t == 0) {   // same wave as h writes -> fence covers them
            __threadfence();
            __hip_atomic_fetch_add(&cn[s], 1, __ATOMIC_RELEASE,
                                   __HIP_MEMORY_SCOPE_AGENT);
            while (__hip_atomic_load(&cn[s], __ATOMIC_ACQUIRE,
                                     __HIP_MEMORY_SCOPE_AGENT) < GROUPS)
                __builtin_amdgcn_s_sleep(1);
        }
        __syncthreads();
        if (t < 128) {  // reload full h (L1-bypassing atomic b64), pack f16
            unsigned long long w = __hip_atomic_load(
                (const unsigned long long*)&hb[2 * t],
                __ATOMIC_RELAXED, __HIP_MEMORY_SCOPE_AGENT);
            float2 hf = __builtin_bit_cast(float2, w);
            union { _Float16 hx[2]; unsigned u_; } pk;
            pk.hx[0] = (_Float16)hf.x;
            pk.hx[1] = (_Float16)hf.y;
            sHp[t] = pk.u_;
        }
        __syncthreads();
        pc = pn;
    }
}

// ---------------------------------------------------------------------------
// head: S[i][j] = sum_h tanh(HF[i][h] + MF[j][h]) * w[h] + outBias
// ---------------------------------------------------------------------------
__global__ __launch_bounds__(256) void head_kernel(const float* __restrict__ HF,
                                                   const float* __restrict__ MF,
                                                   const float* __restrict__ w,
                                                   const float* __restrict__ outb,
                                                   float* __restrict__ S) {
    int i = blockIdx.x;
    __shared__ float sHF[512], sW[512];
    int tid = threadIdx.x;
    sHF[tid] = HF[i * 512 + tid];
    sHF[tid + 256] = HF[i * 512 + 256 + tid];
    sW[tid] = w[tid];
    sW[tid + 256] = w[tid + 256];
    __syncthreads();
    int lane = tid & 63, wv = tid >> 6;
    float ob = outb[0];
    for (int j = wv; j < 512; j += 4) {
        const float* mf = MF + j * 512;
        float acc = 0.f;
#pragma unroll
        for (int r = 0; r < 8; r++) {
            int h = lane + 64 * r;
            float x = sHF[h] + mf[h];
            acc += sW[h] * (1.f - 2.f / (1.f + __expf(2.f * x)));
        }
#pragma unroll
        for (int off = 32; off; off >>= 1) acc += __shfl_down(acc, off);
        if (lane == 0) S[i * 512 + j] = acc + ob;
    }
}

// ---------------------------------------------------------------------------
extern "C" void kernel_launch(void* const* d_in, const int* in_sizes, int n_in,
                              void* d_out, int out_size, void* d_ws, size_t ws_size,
                              hipStream_t stream) {
    const float* emb      = (const float*)d_in[0];
    const float* W_f1     = (const float*)d_in[1];
    const float* U_f1     = (const float*)d_in[2];
    const float* b_f1     = (const float*)d_in[3];
    const float* W_b1     = (const float*)d_in[4];
    const float* U_b1     = (const float*)d_in[5];
    const float* b_b1     = (const float*)d_in[6];
    const float* W_f2     = (const float*)d_in[7];
    const float* U_f2     = (const float*)d_in[8];
    const float* b_f2     = (const float*)d_in[9];
    const float* W_b2     = (const float*)d_in[10];
    const float* U_b2     = (const float*)d_in[11];
    const float* b_b2     = (const float*)d_in[12];
    const float* FOH      = (const float*)d_in[13];
    const float* FOM      = (const float*)d_in[14];
    const float* hidBias  = (const float*)d_in[15];
    const float* outLayer = (const float*)d_in[16];
    const float* outBias  = (const float*)d_in[17];
    float* out = (float*)d_out;

    // workspace carve (16 MB total)
    unsigned int* uf = (unsigned int*)d_ws;          // 4 x 131072 uints = 2MB
    float* f = (float*)d_ws + 524288;
    float* P1   = f;                 // [2][512*1024]  (fwd, bwd contiguous)
    float* P2   = f + 1048576;       // [2][512*1024]
    float* R1   = f + 2097152;       // [2][512*256]
    float* R2   = f + 2359296;       // [2][512*256]
    float* HFb  = f + 2621440;       // 512x512 (includes hidBias)
    float* MFb  = f + 2883584;       // 512x512
    float* Hb   = f + 3145728;       // [2 parity][2 dir][256] = 1024 floats
    int*   cnt  = (int*)(f + 3146752);  // [2][512] = 4KB

    prep4<<<2048, 256, 0, stream>>>(U_f1, U_b1, U_f2, U_b2, uf);

    // layer 1: A = emb (K == halfK, A1 half unused), z=1 reversed
    gemm_cat<<<dim3(16, 8, 2), 256, 0, stream>>>(
        emb, emb, 256, W_f1, W_b1, b_f1, b_b1, P1, P1 + 524288,
        512, 1024, 256, 1);

    hipMemsetAsync(cnt, 0, 2 * 512 * sizeof(int), stream);
    lstm_sync<<<8, 512, 0, stream>>>(uf, P1, R1, Hb, cnt);

    // layer 2: A = concat(rf1, rev rb1), z=1 reversed
    gemm_cat<<<dim3(16, 8, 2), 256, 0, stream>>>(
        R1, R1 + 131072, 256, W_f2, W_b2, b_f2, b_b2, P2, P2 + 524288,
        512, 1024, 512, 1);

    hipMemsetAsync(cnt, 0, 2 * 512 * sizeof(int), stream);
    lstm_sync<<<8, 512, 0, stream>>>(uf + 262144, P2, R2, Hb, cnt);

    // head projections: A = concat(rf2, rev rb2), both z unreversed
    gemm_cat<<<dim3(8, 8, 2), 256, 0, stream>>>(
        R2, R2 + 131072, 256, FOH, FOM, hidBias, nullptr, HFb, MFb,
        512, 512, 512, 0);

    head_kernel<<<512, 256, 0, stream>>>(HFb, MFb, outLayer, outBias, out);
}